// Round 3
// baseline (163.531 us; speedup 1.0000x reference)
//
#include <hip/hip_runtime.h>
#include <stdint.h>

#define WW 256
#define CIN 128
#define COUT 256
#define OHW 64516          // 254*254
#define KTOT 1152          // 128*9
#define BM 256
#define BK 64
#define NSTEP 18           // KTOT/BK
#define NWG 253            // ceil(OHW/BM)
#define BUFSZ 65536        // per tile: A 32KB + B 32KB

typedef __attribute__((ext_vector_type(8))) short short8;
typedef __attribute__((ext_vector_type(4))) float float4v;
typedef __attribute__((ext_vector_type(4))) float f32x4;
typedef __attribute__((ext_vector_type(4))) unsigned int uint4v;

__device__ __forceinline__ short f2bf(float f) {
    unsigned u = __builtin_bit_cast(unsigned, f);
    unsigned r = u + 0x7fffu + ((u >> 16) & 1u);   // RNE
    return (short)(r >> 16);
}

// Wt[co][k'] bf16, k' = q*128 + c. Output-indexed => coalesced 2B writes;
// scattered 4B reads land in the L2-resident 1.2MB source.
__global__ void prep_weights(const int* __restrict__ kq, unsigned short* __restrict__ wt) {
    int o  = blockIdx.x * 256 + threadIdx.x;   // o = co*1152 + kp
    int co = o / KTOT;
    int kp = o - co * KTOT;
    int q  = kp >> 7;
    int c  = kp & 127;
    wt[o] = (unsigned short)f2bf((float)kq[(c * 9 + q) * 256 + co]);
}

__device__ __forceinline__ void gload16(const void* g, void* l) {
    __builtin_amdgcn_global_load_lds(
        (const __attribute__((address_space(1))) unsigned int*)g,
        (__attribute__((address_space(3))) unsigned int*)l, 16, 0, 0);
}

__device__ __forceinline__ unsigned cvtpk(float lo, float hi) {
    unsigned r;
    asm("v_cvt_pk_bf16_f32 %0, %1, %2" : "=v"(r) : "v"(lo), "v"(hi));
    return r;
}

#define SB  __builtin_amdgcn_sched_barrier(0)
#define BAR __builtin_amdgcn_s_barrier()
#define WAIT_VM(n) asm volatile("s_waitcnt vmcnt(" #n ")" ::: "memory")
#define WAIT_LGKM  asm volatile("s_waitcnt lgkmcnt(0)" ::: "memory")

__global__ __launch_bounds__(512, 2) void conv_gemm(
    const float* __restrict__ x,
    const unsigned short* __restrict__ wt,
    const float* __restrict__ scale_p,
    const float* __restrict__ bias,
    float* __restrict__ out)
{
    // Per buffer: A [256 rows][128 B] at +0, B [256 co][128 B] at +32768.
    // Both XOR-swizzled: byte_in_row ^= (row&7)<<4.
    __shared__ __align__(16) char lds[2 * BUFSZ];

    const int tid  = threadIdx.x;
    const int lane = tid & 63;
    const int wave = tid >> 6;

    // bijective XCD-chunked swizzle (m204): nwg=253, q=31, r=5
    const int orig = blockIdx.x;
    const int xcd  = orig & 7;
    const int idx8 = orig >> 3;
    const int wg   = (xcd < 5 ? xcd * 32 : 160 + (xcd - 5) * 31) + idx8;
    const int pbase = wg * BM;

    // ---- A staging: 2 threads/row, 32 fp32 each
    const int arow  = tid >> 1;
    const int ahalf = tid & 1;
    {
    }
    int p = pbase + arow;
    if (p > OHW - 1) p = OHW - 1;              // clamp; stores guarded
    const int oy = p / 254;
    const int ox = p - oy * 254;
    const float* abase = x + (oy * WW + ox) * CIN + ahalf * 32;
    int adst[4];
#pragma unroll
    for (int jw = 0; jw < 4; ++jw)
        adst[jw] = arow * 128 + ((ahalf * 64 + jw * 16) ^ ((arow & 7) << 4));

    // ---- B staging: linear gload_lds dest, inverse-swizzled source
    int bsrc[4];
#pragma unroll
    for (int it = 0; it < 4; ++it) {
        int z    = it * 8192 + wave * 1024 + lane * 16;
        int co   = z >> 7;
        int colb = (z & 127) ^ ((co & 7) << 4);
        bsrc[it] = co * KTOT + (colb >> 1);
    }

    // ---- fragment constants
    const int wr128 = (wave >> 2) * 128;
    const int wc64  = (wave & 3) * 64;
    const int llo   = lane & 15;
    const int lhi16 = (lane >> 4) * 16;

    f32x4 acc[8][4];
#pragma unroll
    for (int m = 0; m < 8; m++)
#pragma unroll
        for (int n = 0; n < 4; n++) acc[m][n] = (f32x4)0.f;

    float4v fr[8];   // A staging registers (single set, tile-deep)

#define ISSUE_A(tk) do {                                                        \
    int q_ = (tk) >> 1;  int ki_ = q_ / 3;  int kj_ = q_ - ki_ * 3;             \
    const float* asrc = abase + (ki_ * WW + kj_) * CIN + (((tk) & 1) << 6);     \
    _Pragma("unroll")                                                           \
    for (int j = 0; j < 8; ++j) fr[j] = ((const float4v*)asrc)[j];              \
} while (0)

#define WRITE_A(bufb) do {                                                      \
    _Pragma("unroll")                                                           \
    for (int jw = 0; jw < 4; ++jw) {                                            \
        uint4v U;                                                               \
        U.x = cvtpk(fr[2*jw][0], fr[2*jw][1]);                                  \
        U.y = cvtpk(fr[2*jw][2], fr[2*jw][3]);                                  \
        U.z = cvtpk(fr[2*jw+1][0], fr[2*jw+1][1]);                              \
        U.w = cvtpk(fr[2*jw+1][2], fr[2*jw+1][3]);                              \
        *(uint4v*)(lds + (bufb) + adst[jw]) = U;                                \
    }                                                                           \
} while (0)

#define GLOAD_B(bufb, tk) do {                                                  \
    _Pragma("unroll")                                                           \
    for (int it = 0; it < 4; ++it)                                              \
        gload16(wt + bsrc[it] + (tk) * 64,                                      \
                lds + (bufb) + 32768 + it * 8192 + wave * 1024);                \
} while (0)

#define COMPUTE(bufb) do {                                                      \
    _Pragma("unroll")                                                           \
    for (int kk = 0; kk < 2; ++kk) {                                            \
        short8 bfr[4];                                                          \
        _Pragma("unroll")                                                       \
        for (int n = 0; n < 4; ++n) {                                           \
            int co  = wc64 + n * 16 + llo;                                      \
            int off = co * 128 + ((kk * 64 + lhi16) ^ ((co & 7) << 4));         \
            bfr[n] = *(const short8*)(lds + (bufb) + 32768 + off);              \
        }                                                                       \
        _Pragma("unroll")                                                       \
        for (int mh = 0; mh < 2; ++mh) {                                        \
            short8 af[4];                                                       \
            _Pragma("unroll")                                                   \
            for (int mi = 0; mi < 4; ++mi) {                                    \
                int row = wr128 + mh * 64 + mi * 16 + llo;                      \
                int off = row * 128 + ((kk * 64 + lhi16) ^ ((row & 7) << 4));   \
                af[mi] = *(const short8*)(lds + (bufb) + off);                  \
            }                                                                   \
            __builtin_amdgcn_s_setprio(1);                                      \
            _Pragma("unroll")                                                   \
            for (int mi = 0; mi < 4; ++mi)                                      \
                _Pragma("unroll")                                               \
                for (int n = 0; n < 4; ++n)                                     \
                    acc[mh * 4 + mi][n] = __builtin_amdgcn_mfma_f32_16x16x32_bf16( \
                        af[mi], bfr[n], acc[mh * 4 + mi][n], 0, 0, 0);          \
            __builtin_amdgcn_s_setprio(0);                                      \
        }                                                                       \
    }                                                                           \
} while (0)

    // ---- prologue
    ISSUE_A(0);
    GLOAD_B(0, 0);
    SB; WAIT_VM(4); SB;        // A(0) regs landed (B(0) may fly); compiler also tracks
    WRITE_A(0);
    ISSUE_A(1);
    GLOAD_B(BUFSZ, 1);
    SB; WAIT_VM(12); SB;       // B(0) landed; A(1)+B(1) in flight
    WAIT_LGKM; SB; BAR; SB;

    // ---- main loop: 2 barriers/tile, counted vmcnt (never 0)
#pragma unroll 2
    for (int t = 0; t < NSTEP - 2; ++t) {
        const int cur = (t & 1) * BUFSZ;
        const int nxt = cur ^ BUFSZ;
        WRITE_A(nxt);          // A(t+1) -> other buffer (compiler waits on fr)
        COMPUTE(cur);
        WAIT_LGKM; SB; BAR; SB;
        ISSUE_A(t + 2);
        GLOAD_B(cur, t + 2);
        SB; WAIT_VM(12); SB;   // B(t+1) landed; A(t+2)+B(t+2) in flight
        BAR; SB;
    }
    // t = 16
    WRITE_A(BUFSZ);            // A(17) -> buf1
    COMPUTE(0);
    WAIT_LGKM; SB; BAR; SB;
    WAIT_VM(0); SB; BAR; SB;   // drain B(17)
    // t = 17
    COMPUTE(BUFSZ);

    // ---- epilogue
    const float scl = scale_p[0];
    const int lhi4 = (lane >> 4) * 4;
#pragma unroll
    for (int n = 0; n < 4; ++n) {
        const int col = wc64 + n * 16 + llo;
        const float bv = bias[col];
#pragma unroll
        for (int m = 0; m < 8; ++m) {
            const int prow = pbase + wr128 + m * 16 + lhi4;
#pragma unroll
            for (int r = 0; r < 4; ++r) {
                const int pp = prow + r;
                if (pp < OHW)
                    out[pp * COUT + col] = acc[m][n][r] * scl + bv;
            }
        }
    }
#undef ISSUE_A
#undef WRITE_A
#undef GLOAD_B
#undef COMPUTE
}

extern "C" void kernel_launch(void* const* d_in, const int* in_sizes, int n_in,
                              void* d_out, int out_size, void* d_ws, size_t ws_size,
                              hipStream_t stream) {
    const float* x     = (const float*)d_in[0];
    const int*   kq    = (const int*)d_in[1];
    const float* scale = (const float*)d_in[2];
    const float* bias  = (const float*)d_in[3];
    float*       out   = (float*)d_out;
    unsigned short* wt = (unsigned short*)d_ws;    // 589,824 B (proven-safe size)

    prep_weights<<<KTOT, 256, 0, stream>>>(kq, wt);
    conv_gemm<<<NWG, 512, 0, stream>>>(x, wt, scale, bias, out);
}

// Round 4
// 154.816 us; speedup vs baseline: 1.0563x; 1.0563x over previous
//
#include <hip/hip_runtime.h>
#include <stdint.h>

#define WW 256
#define CIN 128
#define COUT 256
#define OHW 64516          // 254*254
#define KTOT 1152          // 128*9
#define BM 256
#define BK 64
#define NSTEP 18           // KTOT/BK
#define NWG 253            // ceil(OHW/BM)
#define BUFSZ 65536        // per tile: A 32KB + B 32KB

typedef __attribute__((ext_vector_type(8))) short short8;
typedef __attribute__((ext_vector_type(4))) float float4v;
typedef __attribute__((ext_vector_type(4))) float f32x4;
typedef __attribute__((ext_vector_type(4))) unsigned int uint4v;

__device__ __forceinline__ short f2bf(float f) {
    unsigned u = __builtin_bit_cast(unsigned, f);
    unsigned r = u + 0x7fffu + ((u >> 16) & 1u);   // RNE
    return (short)(r >> 16);
}

// Wt[co][k'] bf16, k' = q*128 + c. Output-indexed => coalesced 2B writes;
// scattered 4B reads land in the L2-resident 1.2MB source. (~few us)
__global__ void prep_weights(const int* __restrict__ kq, unsigned short* __restrict__ wt) {
    int o  = blockIdx.x * 256 + threadIdx.x;   // o = co*1152 + kp
    int co = o / KTOT;
    int kp = o - co * KTOT;
    int q  = kp >> 7;
    int c  = kp & 127;
    wt[o] = (unsigned short)f2bf((float)kq[(c * 9 + q) * 256 + co]);
}

__device__ __forceinline__ void gload16(const void* g, void* l) {
    __builtin_amdgcn_global_load_lds(
        (const __attribute__((address_space(1))) unsigned int*)g,
        (__attribute__((address_space(3))) unsigned int*)l, 16, 0, 0);
}

__device__ __forceinline__ unsigned cvtpk(float lo, float hi) {
    unsigned r;
    asm("v_cvt_pk_bf16_f32 %0, %1, %2" : "=v"(r) : "v"(lo), "v"(hi));
    return r;
}

#define SB  __builtin_amdgcn_sched_barrier(0)
#define BAR __builtin_amdgcn_s_barrier()
#define WAIT_VM(n) asm volatile("s_waitcnt vmcnt(" #n ")" ::: "memory")
#define WAIT_LGKM  asm volatile("s_waitcnt lgkmcnt(0)" ::: "memory")

__global__ __launch_bounds__(512, 2) void conv_gemm(
    const float* __restrict__ x,
    const unsigned short* __restrict__ wt,
    const float* __restrict__ scale_p,
    const float* __restrict__ bias,
    float* __restrict__ out)
{
    // Per buffer: A [256 rows][128 B] at +0, B [256 co][128 B] at +32768.
    // Both XOR-swizzled: byte_in_row ^= (row&7)<<4.
    __shared__ __align__(16) char lds[2 * BUFSZ];

    const int tid  = threadIdx.x;
    const int lane = tid & 63;
    const int wave = tid >> 6;

    // bijective XCD-chunked swizzle (m204): nwg=253, q=31, r=5
    const int orig = blockIdx.x;
    const int xcd  = orig & 7;
    const int idx8 = orig >> 3;
    const int wg   = (xcd < 5 ? xcd * 32 : 160 + (xcd - 5) * 31) + idx8;
    const int pbase = wg * BM;

    // ---- A staging: 2 threads/row, 32 fp32 each (8x float4 loads)
    const int arow  = tid >> 1;
    const int ahalf = tid & 1;
    int p = pbase + arow;
    if (p > OHW - 1) p = OHW - 1;              // clamp; stores guarded
    const int oy = p / 254;
    const int ox = p - oy * 254;
    const float* abase = x + (oy * WW + ox) * CIN + ahalf * 32;
    int adst[4];
#pragma unroll
    for (int jw = 0; jw < 4; ++jw)
        adst[jw] = arow * 128 + ((ahalf * 64 + jw * 16) ^ ((arow & 7) << 4));

    // ---- B staging: linear gload_lds dest, inverse-swizzled source
    int bsrc[4];
#pragma unroll
    for (int it = 0; it < 4; ++it) {
        int z    = it * 8192 + wave * 1024 + lane * 16;
        int co   = z >> 7;
        int colb = (z & 127) ^ ((co & 7) << 4);
        bsrc[it] = co * KTOT + (colb >> 1);
    }

    // ---- fragment constants
    const int wr128 = (wave >> 2) * 128;
    const int wc64  = (wave & 3) * 64;
    const int llo   = lane & 15;
    const int lhi16 = (lane >> 4) * 16;

    f32x4 acc[8][4];
#pragma unroll
    for (int m = 0; m < 8; m++)
#pragma unroll
        for (int n = 0; n < 4; n++) acc[m][n] = (f32x4)0.f;

    float4v fr[8];       // A staging regs (one K-tile deep)
    short8  af[4], bfr[4];

#define ISSUE_A(lo_, tk) do {                                                   \
    int q_ = (tk) >> 1;  int ki_ = q_ / 3;  int kj_ = q_ - ki_ * 3;             \
    const float* asrc = abase + (ki_ * WW + kj_) * CIN + (((tk) & 1) << 6);     \
    _Pragma("unroll")                                                           \
    for (int j = 0; j < 4; ++j) fr[(lo_) + j] = ((const float4v*)asrc)[(lo_) + j]; \
} while (0)

#define WRITE_A(bufb, jlo) do {                                                 \
    _Pragma("unroll")                                                           \
    for (int jw = (jlo); jw < (jlo) + 2; ++jw) {                                \
        uint4v U;                                                               \
        U.x = cvtpk(fr[2*jw][0], fr[2*jw][1]);                                  \
        U.y = cvtpk(fr[2*jw][2], fr[2*jw][3]);                                  \
        U.z = cvtpk(fr[2*jw+1][0], fr[2*jw+1][1]);                              \
        U.w = cvtpk(fr[2*jw+1][2], fr[2*jw+1][3]);                              \
        *(uint4v*)(lds + (bufb) + adst[jw]) = U;                                \
    }                                                                           \
} while (0)

#define GLOAD_B(bufb, tk) do {                                                  \
    _Pragma("unroll")                                                           \
    for (int it = 0; it < 4; ++it)                                              \
        gload16(wt + bsrc[it] + (tk) * 64,                                      \
                lds + (bufb) + 32768 + it * 8192 + wave * 1024);                \
} while (0)

#define READ_B(bufb, kk) do {                                                   \
    _Pragma("unroll")                                                           \
    for (int n = 0; n < 4; ++n) {                                               \
        int co  = wc64 + n * 16 + llo;                                          \
        int off = co * 128 + (((kk) * 64 + lhi16) ^ ((co & 7) << 4));           \
        bfr[n] = *(const short8*)(lds + (bufb) + 32768 + off);                  \
    }                                                                           \
} while (0)

#define READ_A(bufb, mh, kk) do {                                               \
    _Pragma("unroll")                                                           \
    for (int mi = 0; mi < 4; ++mi) {                                            \
        int row = wr128 + (mh) * 64 + mi * 16 + llo;                            \
        int off = row * 128 + (((kk) * 64 + lhi16) ^ ((row & 7) << 4));         \
        af[mi] = *(const short8*)(lds + (bufb) + off);                          \
    }                                                                           \
} while (0)

#define MFMA16(mh) do {                                                         \
    __builtin_amdgcn_s_setprio(1);                                              \
    _Pragma("unroll")                                                           \
    for (int mi = 0; mi < 4; ++mi)                                              \
        _Pragma("unroll")                                                       \
        for (int n = 0; n < 4; ++n)                                             \
            acc[(mh) * 4 + mi][n] = __builtin_amdgcn_mfma_f32_16x16x32_bf16(    \
                af[mi], bfr[n], acc[(mh) * 4 + mi][n], 0, 0, 0);                \
    __builtin_amdgcn_s_setprio(0);                                              \
} while (0)

// One K-tile = 4 phases: (mh,kk) = (0,0),(1,0),(0,1),(1,1), 16 MFMA each.
// Staging of tile TK1 into NXT interleaved: ph0 issues B-gload + A-loads 0..3,
// ph1 issues A-loads 4..7, ph2 vmcnt(4)+write A-half0, ph3 vmcnt(0)+write A-half1.
#define TILE(CUR, NXT, TK1, DOSTAGE) do {                                       \
    /* ---- ph0: (0,0) */                                                       \
    READ_B(CUR, 0); READ_A(CUR, 0, 0);                                          \
    if (DOSTAGE) { GLOAD_B(NXT, TK1); ISSUE_A(0, TK1); }                        \
    SB; BAR; WAIT_LGKM; SB; MFMA16(0); SB; BAR; SB;                             \
    /* ---- ph1: (1,0) */                                                       \
    READ_A(CUR, 1, 0);                                                          \
    if (DOSTAGE) { ISSUE_A(4, TK1); }                                           \
    SB; BAR; WAIT_LGKM; SB; MFMA16(1); SB; BAR; SB;                             \
    /* ---- ph2: (0,1) */                                                       \
    READ_B(CUR, 1); READ_A(CUR, 0, 1);                                          \
    if (DOSTAGE) { WAIT_VM(4); WRITE_A(NXT, 0); }                               \
    SB; BAR; WAIT_LGKM; SB; MFMA16(0); SB; BAR; SB;                             \
    /* ---- ph3: (1,1) */                                                       \
    READ_A(CUR, 1, 1);                                                          \
    if (DOSTAGE) { WAIT_VM(0); WRITE_A(NXT, 2); }                               \
    SB; BAR; WAIT_LGKM; SB; MFMA16(1); SB; BAR; SB;                             \
} while (0)

    // ---- prologue: stage tile 0 into buf0, drain, barrier
    GLOAD_B(0, 0);
    ISSUE_A(0, 0);
    ISSUE_A(4, 0);
    WAIT_VM(0);
    WRITE_A(0, 0);
    WRITE_A(0, 2);
    WAIT_LGKM; SB; BAR; SB;

    // ---- main loop: tiles 0..15 (staged), 16 (stages 17), 17 (compute-only)
#pragma unroll 2
    for (int t = 0; t < 16; t += 2) {
        TILE(0,     BUFSZ, t + 1, 1);
        TILE(BUFSZ, 0,     t + 2, 1);
    }
    TILE(0,     BUFSZ, 17, 1);
    TILE(BUFSZ, 0,     0,  0);

    // ---- epilogue: n-innermost so 4 stores cover 64 contiguous cols (full lines)
    const float scl = scale_p[0];
    const int lhi4 = (lane >> 4) * 4;
    float bv[4];
#pragma unroll
    for (int n = 0; n < 4; ++n) bv[n] = bias[wc64 + n * 16 + llo];
#pragma unroll
    for (int m = 0; m < 8; ++m) {
#pragma unroll
        for (int r = 0; r < 4; ++r) {
            const int pp = pbase + wr128 + m * 16 + lhi4 + r;
            if (pp < OHW) {
#pragma unroll
                for (int n = 0; n < 4; ++n)
                    out[pp * COUT + wc64 + n * 16 + llo] = acc[m][n][r] * scl + bv[n];
            }
        }
    }
#undef ISSUE_A
#undef WRITE_A
#undef GLOAD_B
#undef READ_B
#undef READ_A
#undef MFMA16
#undef TILE
}

extern "C" void kernel_launch(void* const* d_in, const int* in_sizes, int n_in,
                              void* d_out, int out_size, void* d_ws, size_t ws_size,
                              hipStream_t stream) {
    const float* x     = (const float*)d_in[0];
    const int*   kq    = (const int*)d_in[1];
    const float* scale = (const float*)d_in[2];
    const float* bias  = (const float*)d_in[3];
    float*       out   = (float*)d_out;
    unsigned short* wt = (unsigned short*)d_ws;    // 589,824 B (proven-safe size)

    prep_weights<<<KTOT, 256, 0, stream>>>(kq, wt);
    conv_gemm<<<NWG, 512, 0, stream>>>(x, wt, scale, bias, out);
}

// Round 5
// 137.646 us; speedup vs baseline: 1.1881x; 1.1247x over previous
//
#include <hip/hip_runtime.h>
#include <stdint.h>

#define WW 256
#define CIN 128
#define COUT 256
#define OHW 64516          // 254*254
#define KTOT 1152          // 128*9
#define BM 256
#define BK 64
#define NSTEP 18           // KTOT/BK
#define NWG 253            // ceil(OHW/BM)
#define BUFSZ 65536        // per tile: A 32KB + B 32KB

typedef __attribute__((ext_vector_type(8))) short short8;
typedef __attribute__((ext_vector_type(4))) float float4v;
typedef __attribute__((ext_vector_type(4))) float f32x4;
typedef __attribute__((ext_vector_type(2))) unsigned int uint2v;

__device__ __forceinline__ short f2bf(float f) {
    unsigned u = __builtin_bit_cast(unsigned, f);
    unsigned r = u + 0x7fffu + ((u >> 16) & 1u);   // RNE
    return (short)(r >> 16);
}

// Wt[co][k'] bf16, k' = q*128 + c. Output-indexed => coalesced 2B writes;
// scattered 4B reads land in the L2-resident 1.2MB source. (~few us)
__global__ void prep_weights(const int* __restrict__ kq, unsigned short* __restrict__ wt) {
    int o  = blockIdx.x * 256 + threadIdx.x;   // o = co*1152 + kp
    int co = o / KTOT;
    int kp = o - co * KTOT;
    int q  = kp >> 7;
    int c  = kp & 127;
    wt[o] = (unsigned short)f2bf((float)kq[(c * 9 + q) * 256 + co]);
}

__device__ __forceinline__ void gload16(const void* g, void* l) {
    __builtin_amdgcn_global_load_lds(
        (const __attribute__((address_space(1))) unsigned int*)g,
        (__attribute__((address_space(3))) unsigned int*)l, 16, 0, 0);
}

__device__ __forceinline__ unsigned cvtpk(float lo, float hi) {
    unsigned r;
    asm("v_cvt_pk_bf16_f32 %0, %1, %2" : "=v"(r) : "v"(lo), "v"(hi));
    return r;
}

#define SB  __builtin_amdgcn_sched_barrier(0)
#define BAR __builtin_amdgcn_s_barrier()
#define WAIT_VM(n) asm volatile("s_waitcnt vmcnt(" #n ")" ::: "memory")
#define WAIT_LGKM  asm volatile("s_waitcnt lgkmcnt(0)" ::: "memory")

__global__ __launch_bounds__(512, 2) void conv_gemm(
    const float* __restrict__ x,
    const unsigned short* __restrict__ wt,
    const float* __restrict__ scale_p,
    const float* __restrict__ bias,
    float* __restrict__ out)
{
    // Per buffer: A [256 rows][128 B] at +0, B [256 co][128 B] at +32768.
    // Both XOR-swizzled: byte_in_row ^= (row&7)<<4.
    __shared__ __align__(16) char lds[2 * BUFSZ];

    const int tid  = threadIdx.x;
    const int lane = tid & 63;
    const int wave = tid >> 6;

    // bijective XCD-chunked swizzle (m204): nwg=253, q=31, r=5
    const int orig = blockIdx.x;
    const int xcd  = orig & 7;
    const int idx8 = orig >> 3;
    const int wg   = (xcd < 5 ? xcd * 32 : 160 + (xcd - 5) * 31) + idx8;
    const int pbase = wg * BM;

    // ---- A staging: COALESCED mapping — 16 threads/row, 16 B each.
    // Round r (r=0..7): row = (tid>>4) + r*32, float4 idx = tid&15.
    // Lane-adjacent => address-adjacent (256 B runs), vs. the round-4
    // 2-thr/row mapping whose wave-loads hit 64 scattered cache lines.
    const int acol16 = tid & 15;
    const int arow0  = tid >> 4;               // 0..31
    int arowbase[8];
#pragma unroll
    for (int r = 0; r < 8; ++r) {
        int p = pbase + arow0 + r * 32;
        if (p > OHW - 1) p = OHW - 1;          // clamp; stores guarded
        int oy = p / 254;
        int ox = p - oy * 254;
        arowbase[r] = (oy * WW + ox) * CIN;    // float index of pixel base
    }
    const int aswz  = (arow0 & 7) << 4;
    const int adst0 = arow0 * 128 + ((acol16 * 8) ^ aswz);   // + r*4096

    // ---- B staging: linear gload_lds dest, inverse-swizzled source
    int bsrc[4];
#pragma unroll
    for (int it = 0; it < 4; ++it) {
        int z    = it * 8192 + wave * 1024 + lane * 16;
        int co   = z >> 7;
        int colb = (z & 127) ^ ((co & 7) << 4);
        bsrc[it] = co * KTOT + (colb >> 1);
    }

    // ---- fragment constants
    const int wr128 = (wave >> 2) * 128;
    const int wc64  = (wave & 3) * 64;
    const int llo   = lane & 15;
    const int lhi16 = (lane >> 4) * 16;

    f32x4 acc[8][4];
#pragma unroll
    for (int m = 0; m < 8; m++)
#pragma unroll
        for (int n = 0; n < 4; n++) acc[m][n] = (f32x4)0.f;

    float4v fr[8];       // A staging regs (one K-tile deep)
    short8  af[4], bfr[4];

#define ISSUE_A(lo_, tk) do {                                                   \
    int q_ = (tk) >> 1;  int ki_ = q_ / 3;  int kj_ = q_ - ki_ * 3;             \
    int aoff = (ki_ * WW + kj_) * CIN + (((tk) & 1) << 6) + acol16 * 4;         \
    _Pragma("unroll")                                                           \
    for (int r = (lo_); r < (lo_) + 4; ++r)                                     \
        fr[r] = *(const float4v*)(x + arowbase[r] + aoff);                      \
} while (0)

#define WRITE_A(bufb, lo_) do {                                                 \
    _Pragma("unroll")                                                           \
    for (int r = (lo_); r < (lo_) + 4; ++r) {                                   \
        uint2v U;                                                               \
        U.x = cvtpk(fr[r][0], fr[r][1]);                                        \
        U.y = cvtpk(fr[r][2], fr[r][3]);                                        \
        *(uint2v*)(lds + (bufb) + adst0 + r * 4096) = U;                        \
    }                                                                           \
} while (0)

#define GLOAD_B(bufb, tk) do {                                                  \
    _Pragma("unroll")                                                           \
    for (int it = 0; it < 4; ++it)                                              \
        gload16(wt + bsrc[it] + (tk) * 64,                                      \
                lds + (bufb) + 32768 + it * 8192 + wave * 1024);                \
} while (0)

#define READ_B(bufb, kk) do {                                                   \
    _Pragma("unroll")                                                           \
    for (int n = 0; n < 4; ++n) {                                               \
        int co  = wc64 + n * 16 + llo;                                          \
        int off = co * 128 + (((kk) * 64 + lhi16) ^ ((co & 7) << 4));           \
        bfr[n] = *(const short8*)(lds + (bufb) + 32768 + off);                  \
    }                                                                           \
} while (0)

#define READ_A(bufb, mh, kk) do {                                               \
    _Pragma("unroll")                                                           \
    for (int mi = 0; mi < 4; ++mi) {                                            \
        int row = wr128 + (mh) * 64 + mi * 16 + llo;                            \
        int off = row * 128 + (((kk) * 64 + lhi16) ^ ((row & 7) << 4));         \
        af[mi] = *(const short8*)(lds + (bufb) + off);                          \
    }                                                                           \
} while (0)

#define MFMA16(mh) do {                                                         \
    __builtin_amdgcn_s_setprio(1);                                              \
    _Pragma("unroll")                                                           \
    for (int mi = 0; mi < 4; ++mi)                                              \
        _Pragma("unroll")                                                       \
        for (int n = 0; n < 4; ++n)                                             \
            acc[(mh) * 4 + mi][n] = __builtin_amdgcn_mfma_f32_16x16x32_bf16(    \
                af[mi], bfr[n], acc[(mh) * 4 + mi][n], 0, 0, 0);                \
    __builtin_amdgcn_s_setprio(0);                                              \
} while (0)

// One K-tile = 4 phases: (mh,kk) = (0,0),(1,0),(0,1),(1,1), 16 MFMA each.
// Staging of tile TK1 into NXT: ph0 issues B-gload + A rounds 0..3,
// ph1 issues A rounds 4..7, ph2 vmcnt(4) (B + A0..3 done, 2 phases of
// flight) + write half0, ph3 vmcnt(0) (A4..7, 2 phases) + write half1.
#define TILE(CUR, NXT, TK1, DOSTAGE) do {                                       \
    /* ---- ph0: (0,0) */                                                       \
    READ_B(CUR, 0); READ_A(CUR, 0, 0);                                          \
    if (DOSTAGE) { GLOAD_B(NXT, TK1); ISSUE_A(0, TK1); }                        \
    SB; BAR; WAIT_LGKM; SB; MFMA16(0); SB; BAR; SB;                             \
    /* ---- ph1: (1,0) */                                                       \
    READ_A(CUR, 1, 0);                                                          \
    if (DOSTAGE) { ISSUE_A(4, TK1); }                                           \
    SB; BAR; WAIT_LGKM; SB; MFMA16(1); SB; BAR; SB;                             \
    /* ---- ph2: (0,1) */                                                       \
    READ_B(CUR, 1); READ_A(CUR, 0, 1);                                          \
    if (DOSTAGE) { WAIT_VM(4); WRITE_A(NXT, 0); }                               \
    SB; BAR; WAIT_LGKM; SB; MFMA16(0); SB; BAR; SB;                             \
    /* ---- ph3: (1,1) */                                                       \
    READ_A(CUR, 1, 1);                                                          \
    if (DOSTAGE) { WAIT_VM(0); WRITE_A(NXT, 4); }                               \
    SB; BAR; WAIT_LGKM; SB; MFMA16(1); SB; BAR; SB;                             \
} while (0)

    // ---- prologue: stage tile 0 into buf0, drain, barrier
    GLOAD_B(0, 0);
    ISSUE_A(0, 0);
    ISSUE_A(4, 0);
    WAIT_VM(0);
    WRITE_A(0, 0);
    WRITE_A(0, 4);
    WAIT_LGKM; SB; BAR; SB;

    // ---- main loop: tiles 0..15 (staged), 16 (stages 17), 17 (compute-only)
#pragma unroll 2
    for (int t = 0; t < 16; t += 2) {
        TILE(0,     BUFSZ, t + 1, 1);
        TILE(BUFSZ, 0,     t + 2, 1);
    }
    TILE(0,     BUFSZ, 17, 1);
    TILE(BUFSZ, 0,     0,  0);

    // ---- epilogue: n-innermost so 4 stores cover 64 contiguous cols (full lines)
    const float scl = scale_p[0];
    const int lhi4 = (lane >> 4) * 4;
    float bv[4];
#pragma unroll
    for (int n = 0; n < 4; ++n) bv[n] = bias[wc64 + n * 16 + llo];
#pragma unroll
    for (int m = 0; m < 8; ++m) {
#pragma unroll
        for (int r = 0; r < 4; ++r) {
            const int pp = pbase + wr128 + m * 16 + lhi4 + r;
            if (pp < OHW) {
#pragma unroll
                for (int n = 0; n < 4; ++n)
                    out[pp * COUT + wc64 + n * 16 + llo] = acc[m][n][r] * scl + bv[n];
            }
        }
    }
#undef ISSUE_A
#undef WRITE_A
#undef GLOAD_B
#undef READ_B
#undef READ_A
#undef MFMA16
#undef TILE
}

extern "C" void kernel_launch(void* const* d_in, const int* in_sizes, int n_in,
                              void* d_out, int out_size, void* d_ws, size_t ws_size,
                              hipStream_t stream) {
    const float* x     = (const float*)d_in[0];
    const int*   kq    = (const int*)d_in[1];
    const float* scale = (const float*)d_in[2];
    const float* bias  = (const float*)d_in[3];
    float*       out   = (float*)d_out;
    unsigned short* wt = (unsigned short*)d_ws;    // 589,824 B (proven-safe size)

    prep_weights<<<KTOT, 256, 0, stream>>>(kq, wt);
    conv_gemm<<<NWG, 512, 0, stream>>>(x, wt, scale, bias, out);
}